// Round 4
// baseline (303.534 us; speedup 1.0000x reference)
//
#include <hip/hip_runtime.h>
#include <hip/hip_bf16.h>

#define TD 49
#define BD 16
#define ND 64
#define HD 128

typedef float  f32x4  __attribute__((ext_vector_type(4)));
typedef __bf16 bf16x8 __attribute__((ext_vector_type(8)));
typedef __bf16 bf16x4 __attribute__((ext_vector_type(4)));

// ---------------- workspace layout (bf16 element offsets) ----------------
#define WP_OFF   0u
#define WP_ELEMS 38535168u           // 49*8*128*768  : W' [t][g][h][k] bf16
#define HB_OFF   38535168u           // h  bf16 [B,T,N,H]
#define ACT_ELEMS 6422528u           // 16*49*64*128
#define PB_OFF   44957696u           // p  bf16
#define GB_OFF   51380224u           // g_t bf16 [B,T,H]
#define GT_ELEMS 100352u
#define ZP_OFF   51480576u           // 2048 bf16 zeros (pad source page)
// total = 51482624 elems = 102,965,248 bytes

#define OUT_H    0
#define OUT_CH   6422528
#define OUT_G    12845056
#define OUT_CG   12945408

#define KPAD 136
#define LDS1_BYTES 131072            // A[2][256][64] + B[2][256][64] bf16

__device__ __forceinline__ float sigf(float x) {
    return 1.0f / (1.0f + exp2f(-1.442695041f * x));
}
__device__ __forceinline__ float tanhf_fast(float x) {
    x = fminf(fmaxf(x, -20.f), 20.f);
    float e = exp2f(2.885390082f * x);
    return (e - 1.f) / (e + 1.f);
}
__device__ __forceinline__ void gload16(const void* g, void* l) {
    __builtin_amdgcn_global_load_lds((const __attribute__((address_space(1))) void*)g,
                                     (__attribute__((address_space(3))) void*)l, 16, 0, 0);
}

// ---------------------------------------------------------------------------
// prep_acts: cast h, p, g_t f32 -> bf16 into ws; fill zero page.
// ---------------------------------------------------------------------------
__global__ void prep_acts(const float* __restrict__ h, const float* __restrict__ p,
                          const float* __restrict__ g, __bf16* __restrict__ ws)
{
    unsigned i = blockIdx.x * 256u + threadIdx.x;
    const unsigned HU = ACT_ELEMS / 4u, GU = GT_ELEMS / 4u;
    const float* src;
    unsigned dst;
    if (i < HU)                 { src = h + (size_t)i * 4;          dst = HB_OFF + i * 4; }
    else if (i < 2u*HU)         { unsigned j = i - HU;   src = p + (size_t)j * 4; dst = PB_OFF + j * 4; }
    else if (i < 2u*HU + GU)    { unsigned j = i - 2u*HU; src = g + (size_t)j * 4; dst = GB_OFF + j * 4; }
    else if (i < 2u*HU + GU + 512u) {
        unsigned j = i - 2u*HU - GU;
        bf16x4 z = {};
        *(bf16x4*)(ws + ZP_OFF + j * 4) = z;
        return;
    } else return;
    f32x4 v = *(const f32x4*)src;
    bf16x4 w;
    w[0] = (__bf16)v[0]; w[1] = (__bf16)v[1]; w[2] = (__bf16)v[2]; w[3] = (__bf16)v[3];
    *(bf16x4*)(ws + dst) = w;
}

// ---------------------------------------------------------------------------
// prep_w: transpose+cast weights into W'[t][g][h=128][k=768] bf16,
//         k-order = [U | Wt0 | Wt1 | Wt2 | Ws | Zt].
// grid = 49*8*12 (one 64-k chunk per block).
// ---------------------------------------------------------------------------
__global__ __launch_bounds__(256) void prep_w(
    const float* __restrict__ U, const float* __restrict__ Wt,
    const float* __restrict__ Ws, const float* __restrict__ Zt,
    __bf16* __restrict__ wp)
{
    __shared__ __bf16 tile[64 * 132];
    int bid = blockIdx.x;
    int tg  = bid / 12;              // t*8+g
    int c   = bid % 12;
    int t   = tg >> 3, g = tg & 7;
    int gt  = g * TD + t;
    int tid = threadIdx.x;
    int k0  = c * 64;

#pragma unroll
    for (int u = 0; u < 8; ++u) {
        int unit = u * 256 + tid;    // [0,2048): 64 k x 32 f32x4
        int kk = unit >> 5;
        int h4 = (unit & 31) << 2;
        int k  = k0 + kk;
        const float* src;
        if (k < 128)      src = U  + ((size_t)(gt * 128 + k)       << 7);
        else if (k < 512) src = Wt + ((size_t)(gt * 384 + (k-128)) << 7);
        else if (k < 640) src = Ws + ((size_t)(gt * 128 + (k-512)) << 7);
        else              src = Zt + ((size_t)(gt * 128 + (k-640)) << 7);
        f32x4 v = *(const f32x4*)(src + h4);
        bf16x4 w;
        w[0] = (__bf16)v[0]; w[1] = (__bf16)v[1]; w[2] = (__bf16)v[2]; w[3] = (__bf16)v[3];
        *(bf16x4*)(tile + kk * 132 + h4) = w;
    }
    __syncthreads();
#pragma unroll
    for (int u = 0; u < 2; ++u) {
        int unit = u * 256 + tid;    // [0,512): 128 h x 4 k-groups
        int hh = unit >> 2;
        int kg = unit & 3;
        bf16x8 v0, v1;
#pragma unroll
        for (int j = 0; j < 8; ++j) v0[j] = tile[(kg * 16 + j) * 132 + hh];
#pragma unroll
        for (int j = 0; j < 8; ++j) v1[j] = tile[(kg * 16 + 8 + j) * 132 + hh];
        __bf16* dst = wp + (size_t)(tg * 128 + hh) * 768 + k0 + kg * 16;
        *(bf16x8*)dst       = v0;
        *(bf16x8*)(dst + 8) = v1;
    }
}

// ---------------------------------------------------------------------------
// Phase 1: 256x256-tile GEMM over K=768 + fused gates.
// grid = 49 t x 4 mtile x 4 ntile (XCD-swizzled). 512 thr = 8 waves (4M x 2H).
// T3/T4/T5 schedule: per K-step {ds_read frags -> lgkmcnt(0)+SB -> s_barrier ->
// STAGE tile ks+2 into freed buffer -> SB -> setprio(1) MFMA setprio(0) ->
// vmcnt(8) counted -> s_barrier}.  Tile j always lives in buf j&1.
// ---------------------------------------------------------------------------
__global__ __launch_bounds__(512, 1) void phase1_kernel(
    const __bf16* __restrict__ ws,
    const float* __restrict__ c_h, const float* __restrict__ c_g_t,
    const float* __restrict__ bias, float* __restrict__ out)
{
    extern __shared__ __bf16 smem[];      // A: [0,32768) elems, B: [32768,65536)
    const __bf16* hb = ws + HB_OFF;
    const __bf16* pb = ws + PB_OFF;
    const __bf16* gb = ws + GB_OFF;
    const __bf16* wp = ws + WP_OFF;
    const __bf16* zp = ws + ZP_OFF;

    int bid = blockIdx.x;
    int swz = (bid & 7) * 98 + (bid >> 3);   // XCD swizzle, bijective (784 = 8*98)
    int t     = swz >> 4;
    int rem   = swz & 15;
    int mtile = rem >> 2, ntile = rem & 3;

    int tid  = threadIdx.x;
    int wave = tid >> 6, lane = tid & 63;
    int wm = wave >> 1, wh = wave & 1;
    int lg = lane >> 4, l16 = lane & 15;

    // staging per-lane constants: chunk = wave + it*8 covers rows R0 + it*64
    const int R0   = (wave << 3) + (lane >> 3);        // n in [0,64)
    const int k16s = ((lane & 7) ^ (R0 & 7)) << 3;     // pre-swizzled k elem off
    const int n    = R0;

    f32x4 acc[4][8];
    const f32x4 vzero = {0.f, 0.f, 0.f, 0.f};
#pragma unroll
    for (int mi = 0; mi < 4; ++mi)
#pragma unroll
        for (int g = 0; g < 8; ++g) acc[mi][g] = vzero;

    // fragment read bases (byte offsets into a buffer)
    int rbA[4], rsA[4], rbB[8], rsB[8];
#pragma unroll
    for (int mi = 0; mi < 4; ++mi) {
        int row = wm * 64 + mi * 16 + l16;
        rbA[mi] = row << 7;
        rsA[mi] = (row & 7) << 4;
    }
#pragma unroll
    for (int g = 0; g < 8; ++g) {
        int row = g * 32 + wh * 16 + l16;
        rbB[g] = row << 7;
        rsB[g] = (row & 7) << 4;
    }
    const int kb0 = lg << 4;

#define STAGE_A(BUF, KS) do {                                                   \
        int s_   = (KS) >> 1;                                                   \
        int koff = (((KS) & 1) << 6) + k16s;                                    \
        _Pragma("unroll")                                                       \
        for (int it = 0; it < 4; ++it) {                                        \
            int b_  = mtile * 4 + it;                                           \
            int bt_ = b_ * TD + t;                                              \
            const __bf16* src;                                                  \
            if (s_ == 0)      src = pb + ((bt_ * ND + n) << 7) + koff;          \
            else if (s_ == 1) src = (t > 0)    ? hb + (((bt_-1) * ND + n) << 7) + koff : zp; \
            else if (s_ == 2) src = hb + ((bt_ * ND + n) << 7) + koff;          \
            else if (s_ == 3) src = (t < TD-1) ? hb + (((bt_+1) * ND + n) << 7) + koff : zp; \
            else if (s_ == 4) src = (n > 0)    ? hb + ((bt_ * ND + n - 1) << 7) + koff : zp; \
            else              src = gb + (bt_ << 7) + koff;                     \
            __bf16* dst = smem + (BUF) * 16384 + (wave + it * 8) * 512;         \
            gload16(src, dst);                                                  \
        }                                                                       \
    } while (0)

#define STAGE_B(BUF, KS) do {                                                   \
        _Pragma("unroll")                                                       \
        for (int it = 0; it < 4; ++it) {                                        \
            int np = R0 + it * 64;                                              \
            int g_ = np >> 5, hc = np & 31;                                     \
            const __bf16* src = wp + (size_t)((t * 8 + g_) * 128 + ntile * 32 + hc) * 768 \
                                   + ((KS) << 6) + k16s;                        \
            __bf16* dst = smem + 32768 + (BUF) * 16384 + (wave + it * 8) * 512; \
            gload16(src, dst);                                                  \
        }                                                                       \
    } while (0)

    // prologue: tiles 0 and 1 in flight (8 loads each)
    STAGE_A(0, 0);
    STAGE_B(0, 0);
    STAGE_A(1, 1);
    STAGE_B(1, 1);
    asm volatile("s_waitcnt vmcnt(8)" ::: "memory");   // tile 0 landed
    __builtin_amdgcn_sched_barrier(0);
    __builtin_amdgcn_s_barrier();

    for (int ks = 0; ks < 12; ++ks) {
        const int buf = ks & 1;
        const char* Ab = (const char*)(smem + buf * 16384);
        const char* Bb = (const char*)(smem + 32768 + buf * 16384);

        // ---- ds_read all 24 fragments of tile ks into registers
        bf16x8 af[2][4], bfr[2][8];
#pragma unroll
        for (int ks32 = 0; ks32 < 2; ++ks32) {
#pragma unroll
            for (int mi = 0; mi < 4; ++mi)
                af[ks32][mi] = *(const bf16x8*)(Ab + rbA[mi] + (((ks32 << 6) + kb0) ^ rsA[mi]));
#pragma unroll
            for (int g = 0; g < 8; ++g)
                bfr[ks32][g] = *(const bf16x8*)(Bb + rbB[g] + (((ks32 << 6) + kb0) ^ rsB[g]));
        }
        asm volatile("s_waitcnt lgkmcnt(0)" ::: "memory");
        __builtin_amdgcn_sched_barrier(0);             // rule #18
        __builtin_amdgcn_s_barrier();                  // all waves done reading buf

        // ---- overwrite freed buffer with tile ks+2 (stays in flight over MFMA)
        if (ks + 2 < 12) {
            STAGE_A(buf, ks + 2);
            STAGE_B(buf, ks + 2);
        }
        __builtin_amdgcn_sched_barrier(0);             // loads issued before MFMA

        __builtin_amdgcn_s_setprio(1);
#pragma unroll
        for (int ks32 = 0; ks32 < 2; ++ks32)
#pragma unroll
            for (int mi = 0; mi < 4; ++mi)
#pragma unroll
                for (int g = 0; g < 8; ++g)
                    acc[mi][g] = __builtin_amdgcn_mfma_f32_16x16x32_bf16(af[ks32][mi], bfr[ks32][g], acc[mi][g], 0, 0, 0);
        __builtin_amdgcn_s_setprio(0);

        if (ks < 11) {
            if (ks + 2 < 12) {
                asm volatile("s_waitcnt vmcnt(8)" ::: "memory");  // tile ks+1 landed, ks+2 in flight
            } else {
                asm volatile("s_waitcnt vmcnt(0)" ::: "memory");  // tail: tile 11 landed
            }
            __builtin_amdgcn_sched_barrier(0);
            __builtin_amdgcn_s_barrier();
        }
    }

    // ---- epilogue: gates + cell update, in-register (8 gates per lane) ----
    const int hcol = ntile * 32 + wh * 16 + l16;
    float bv[8];
#pragma unroll
    for (int g = 0; g < 8; ++g) bv[g] = bias[(g * TD + t) * HD + hcol];

#pragma unroll
    for (int mi = 0; mi < 4; ++mi) {
#pragma unroll
        for (int r = 0; r < 4; ++r) {
            int RG = mtile * 256 + wm * 64 + mi * 16 + lg * 4 + r;
            int b  = RG >> 6, nn = RG & 63;
            int bt = b * TD + t;
            int base = ((bt * ND + nn) << 7) + hcol;
            float pre[8];
#pragma unroll
            for (int g = 0; g < 8; ++g) pre[g] = acc[mi][g][r] + bv[g];
            float i_  = sigf(pre[0]);
            float flt = sigf(pre[1]);
            float fft = sigf(pre[2]);
            float frt = sigf(pre[3]);
            float fs  = sigf(pre[4]);
            float gn  = sigf(pre[5]);
            float on  = sigf(pre[6]);
            float cn  = tanhf_fast(pre[7]);
            float ccur = c_h[base];
            float ctb  = (t > 0)      ? c_h[base - ND * HD] : 0.f;
            float cta  = (t < TD - 1) ? c_h[base + ND * HD] : 0.f;
            float csb  = (nn > 0)     ? c_h[base - HD]      : 0.f;
            float cg   = c_g_t[(bt << 7) + hcol];
            float cnew = i_ * cn + flt * ctb + fft * ccur + frt * cta + fs * csb + gn * cg;
            float hnew = on * tanhf_fast(cnew);
            out[OUT_H  + base] = hnew;
            out[OUT_CH + base] = cnew;
        }
    }
#undef STAGE_A
#undef STAGE_B
}

// ---------------------------------------------------------------------------
// Phase 2: per (b,t) workgroup.  f_gtf GEMM + bone-mean reduction + tiny dots.
// ---------------------------------------------------------------------------
__global__ __launch_bounds__(256, 2) void phase2_kernel(
    const float* __restrict__ g_t, const float* __restrict__ c_g_t,
    const float* __restrict__ Wg,  const float* __restrict__ Zg,
    const float* __restrict__ bg,  float* __restrict__ out)
{
    __shared__ __bf16 A2[64 * KPAD];
    __shared__ __bf16 Wb[128 * KPAD];
    __shared__ float  gts[128];
    __shared__ float  hm[128];
    __shared__ float  dots[5][128];
    __shared__ float  ps[2][128];
    __shared__ float  red[4][128];

    const int bid  = blockIdx.x;
    const int t    = bid >> 4;
    const int b    = bid & 15;
    const int tid  = threadIdx.x;
    const int wv   = tid >> 6;
    const int lane = tid & 63;
    const int lg   = lane >> 4;
    const int l16  = lane & 15;
    const int bt   = b * TD + t;

    const float* hn  = out + OUT_H;
    const float* chn = out + OUT_CH;

#pragma unroll
    for (int j = 0; j < 8; ++j) {
        int fid = j * 256 + tid;
        int r   = fid >> 5;
        int k   = (fid & 31) << 2;
        f32x4 v = *(const f32x4*)(hn + ((bt * ND + r) << 7) + k);
        bf16x4 w;
        w[0] = (__bf16)v[0]; w[1] = (__bf16)v[1]; w[2] = (__bf16)v[2]; w[3] = (__bf16)v[3];
        *(bf16x4*)(A2 + r * KPAD + k) = w;
    }
    if (tid < 128) gts[tid] = g_t[(bt << 7) + tid];
    __syncthreads();

    {
        int c = tid & 127, half = tid >> 7;
        float sum_ = 0.f;
        for (int r2 = 0; r2 < 32; ++r2) sum_ += (float)A2[(half * 32 + r2) * KPAD + c];
        ps[half][c] = sum_;
    }
    __syncthreads();
    if (tid < 128) hm[tid] = (ps[0][tid] + ps[1][tid]) * (1.f / 64.f);

    for (int m = 0; m < 5; ++m) {
        const float* M = (m < 3) ? (Zg + ((size_t)(m * TD + t) << 14))
                                 : (Wg + ((size_t)((m - 2) * TD + t) << 14));
        const bool use_hm = (m >= 3);
        __syncthreads();
#pragma unroll
        for (int j = 0; j < 16; ++j) {
            int fid = j * 256 + tid;
            int k   = fid >> 5;
            int c4  = (fid & 31) << 2;
            f32x4 v = *(const f32x4*)(M + (k << 7) + c4);
            bf16x4 w;
            w[0] = (__bf16)v[0]; w[1] = (__bf16)v[1]; w[2] = (__bf16)v[2]; w[3] = (__bf16)v[3];
            *(bf16x4*)(Wb + (k << 7) + c4) = w;
        }
        __syncthreads();
        {
            int c = tid & 127, half = tid >> 7;
            const float* vec = use_hm ? hm : gts;
            float sum_ = 0.f;
            for (int k = half * 64; k < half * 64 + 64; ++k)
                sum_ += vec[k] * (float)Wb[(k << 7) + c];
            ps[half][c] = sum_;
        }
        __syncthreads();
        if (tid < 128) dots[m][tid] = ps[0][tid] + ps[1][tid];
    }

    {
        const float* M = Wg + ((size_t)t << 14);
        __syncthreads();
#pragma unroll
        for (int j = 0; j < 16; ++j) {
            int fid = j * 256 + tid;
            int k   = fid >> 5;
            int q   = fid & 31;
            f32x4 v = *(const f32x4*)(M + (k << 7) + q * 4);
            int cb = q * 4;
            Wb[(cb + 0) * KPAD + k] = (__bf16)v[0];
            Wb[(cb + 1) * KPAD + k] = (__bf16)v[1];
            Wb[(cb + 2) * KPAD + k] = (__bf16)v[2];
            Wb[(cb + 3) * KPAD + k] = (__bf16)v[3];
        }
        __syncthreads();
    }

    f32x4 acc[8];
    const f32x4 vzero = {0.f, 0.f, 0.f, 0.f};
#pragma unroll
    for (int cf = 0; cf < 8; ++cf) acc[cf] = vzero;
#pragma unroll
    for (int ks = 0; ks < 4; ++ks) {
        int kb = ks * 32 + lg * 8;
        bf16x8 a = *(const bf16x8*)(A2 + (wv * 16 + l16) * KPAD + kb);
#pragma unroll
        for (int cf = 0; cf < 8; ++cf) {
            bf16x8 bfr = *(const bf16x8*)(Wb + (cf * 16 + l16) * KPAD + kb);
            acc[cf] = __builtin_amdgcn_mfma_f32_16x16x32_bf16(a, bfr, acc[cf], 0, 0, 0);
        }
    }

#pragma unroll
    for (int cf = 0; cf < 8; ++cf) {
        int col = cf * 16 + l16;
        float z = dots[0][col] + bg[(0 * TD + t) * HD + col];
        float macc = 0.f;
#pragma unroll
        for (int r = 0; r < 4; ++r) {
            int row = wv * 16 + lg * 4 + r;
            float f  = sigf(acc[cf][r] + z);
            float cv = chn[((bt * ND + row) << 7) + col];
            macc += f * cv;
        }
        macc += __shfl_xor(macc, 16, 64);
        macc += __shfl_xor(macc, 32, 64);
        if (lane < 16) red[wv][col] = macc;
    }
    __syncthreads();
    if (tid < 128) {
        int c = tid;
        float Mn  = (red[0][c] + red[1][c] + red[2][c] + red[3][c]) * (1.f / 64.f);
        float g_g = sigf(dots[3][c] + dots[1][c] + bg[(1 * TD + t) * HD + c]);
        float o_g = sigf(dots[4][c] + dots[2][c] + bg[(2 * TD + t) * HD + c]);
        float cgt = c_g_t[(bt << 7) + c];
        float cgn = Mn + g_g * cgt;
        float gnw = tanhf_fast(cgn) * o_g;
        out[OUT_G  + (bt << 7) + c] = gnw;
        out[OUT_CG + (bt << 7) + c] = cgn;
    }
}

extern "C" void kernel_launch(void* const* d_in, const int* in_sizes, int n_in,
                              void* d_out, int out_size, void* d_ws, size_t ws_size,
                              hipStream_t stream) {
    const float* h     = (const float*)d_in[0];
    const float* c_h   = (const float*)d_in[1];
    const float* p     = (const float*)d_in[2];
    const float* g_t   = (const float*)d_in[3];
    const float* c_g_t = (const float*)d_in[4];
    const float* U     = (const float*)d_in[5];
    const float* Wt    = (const float*)d_in[6];
    const float* Ws    = (const float*)d_in[7];
    const float* Zt    = (const float*)d_in[8];
    const float* b     = (const float*)d_in[9];
    const float* Wg    = (const float*)d_in[10];
    const float* Zg    = (const float*)d_in[11];
    const float* bg    = (const float*)d_in[12];
    float* out = (float*)d_out;
    __bf16* ws = (__bf16*)d_ws;

    // prep: 2*1605632 + 25088 + 512 = 3,236,864 units -> 12644 blocks
    prep_acts<<<12644, 256, 0, stream>>>(h, p, g_t, ws);
    prep_w<<<TD * 8 * 12, 256, 0, stream>>>(U, Wt, Ws, Zt, ws + WP_OFF);

    (void)hipFuncSetAttribute(reinterpret_cast<const void*>(phase1_kernel),
                              hipFuncAttributeMaxDynamicSharedMemorySize, LDS1_BYTES);
    phase1_kernel<<<TD * 16, 512, LDS1_BYTES, stream>>>(ws, c_h, c_g_t, b, out);
    phase2_kernel<<<TD * BD, 256, 0, stream>>>(g_t, c_g_t, Wg, Zg, bg, out);
}

// Round 5
// 288.456 us; speedup vs baseline: 1.0523x; 1.0523x over previous
//
#include <hip/hip_runtime.h>
#include <hip/hip_bf16.h>

#define TD 49
#define BD 16
#define ND 64
#define HD 128

typedef float  f32x4  __attribute__((ext_vector_type(4)));
typedef __bf16 bf16x8 __attribute__((ext_vector_type(8)));
typedef __bf16 bf16x4 __attribute__((ext_vector_type(4)));

// ---------------- workspace layout (bf16 element offsets) ----------------
#define WP_OFF   0u
#define WP_ELEMS 38535168u           // 49*8*128*768  : W' [t][g][h][k] bf16
#define HB_OFF   38535168u           // h  bf16 [B,T,N,H]
#define ACT_ELEMS 6422528u           // 16*49*64*128
#define PB_OFF   44957696u           // p  bf16
#define GB_OFF   51380224u           // g_t bf16 [B,T,H]
#define GT_ELEMS 100352u
#define ZP_OFF   51480576u           // 2048 bf16 zeros (pad source page)
// total = 51482624 elems = 102,965,248 bytes

#define OUT_H    0
#define OUT_CH   6422528
#define OUT_G    12845056
#define OUT_CG   12945408

#define KPAD 136
#define LDS1_BYTES 131072            // A[2][256][64] + B[2][256][64] bf16

__device__ __forceinline__ float sigf(float x) {
    return 1.0f / (1.0f + exp2f(-1.442695041f * x));
}
__device__ __forceinline__ float tanhf_fast(float x) {
    x = fminf(fmaxf(x, -20.f), 20.f);
    float e = exp2f(2.885390082f * x);
    return (e - 1.f) / (e + 1.f);
}
__device__ __forceinline__ void gload16(const void* g, void* l) {
    __builtin_amdgcn_global_load_lds((const __attribute__((address_space(1))) void*)g,
                                     (__attribute__((address_space(3))) void*)l, 16, 0, 0);
}

// ---------------------------------------------------------------------------
// prep_acts: cast h, p, g_t f32 -> bf16 into ws; fill zero page.
// ---------------------------------------------------------------------------
__global__ void prep_acts(const float* __restrict__ h, const float* __restrict__ p,
                          const float* __restrict__ g, __bf16* __restrict__ ws)
{
    unsigned i = blockIdx.x * 256u + threadIdx.x;
    const unsigned HU = ACT_ELEMS / 4u, GU = GT_ELEMS / 4u;
    const float* src;
    unsigned dst;
    if (i < HU)                 { src = h + (size_t)i * 4;          dst = HB_OFF + i * 4; }
    else if (i < 2u*HU)         { unsigned j = i - HU;   src = p + (size_t)j * 4; dst = PB_OFF + j * 4; }
    else if (i < 2u*HU + GU)    { unsigned j = i - 2u*HU; src = g + (size_t)j * 4; dst = GB_OFF + j * 4; }
    else if (i < 2u*HU + GU + 512u) {
        unsigned j = i - 2u*HU - GU;
        bf16x4 z = {};
        *(bf16x4*)(ws + ZP_OFF + j * 4) = z;
        return;
    } else return;
    f32x4 v = *(const f32x4*)src;
    bf16x4 w;
    w[0] = (__bf16)v[0]; w[1] = (__bf16)v[1]; w[2] = (__bf16)v[2]; w[3] = (__bf16)v[3];
    *(bf16x4*)(ws + dst) = w;
}

// ---------------------------------------------------------------------------
// prep_w: transpose+cast weights into W'[t][g][h=128][k=768] bf16,
//         k-order = [U | Wt0 | Wt1 | Wt2 | Ws | Zt].
// grid = 49*8*12 (one 64-k chunk per block).
// ---------------------------------------------------------------------------
__global__ __launch_bounds__(256) void prep_w(
    const float* __restrict__ U, const float* __restrict__ Wt,
    const float* __restrict__ Ws, const float* __restrict__ Zt,
    __bf16* __restrict__ wp)
{
    __shared__ __bf16 tile[64 * 132];
    int bid = blockIdx.x;
    int tg  = bid / 12;              // t*8+g
    int c   = bid % 12;
    int t   = tg >> 3, g = tg & 7;
    int gt  = g * TD + t;
    int tid = threadIdx.x;
    int k0  = c * 64;

#pragma unroll
    for (int u = 0; u < 8; ++u) {
        int unit = u * 256 + tid;    // [0,2048): 64 k x 32 f32x4
        int kk = unit >> 5;
        int h4 = (unit & 31) << 2;
        int k  = k0 + kk;
        const float* src;
        if (k < 128)      src = U  + ((size_t)(gt * 128 + k)       << 7);
        else if (k < 512) src = Wt + ((size_t)(gt * 384 + (k-128)) << 7);
        else if (k < 640) src = Ws + ((size_t)(gt * 128 + (k-512)) << 7);
        else              src = Zt + ((size_t)(gt * 128 + (k-640)) << 7);
        f32x4 v = *(const f32x4*)(src + h4);
        bf16x4 w;
        w[0] = (__bf16)v[0]; w[1] = (__bf16)v[1]; w[2] = (__bf16)v[2]; w[3] = (__bf16)v[3];
        *(bf16x4*)(tile + kk * 132 + h4) = w;
    }
    __syncthreads();
#pragma unroll
    for (int u = 0; u < 2; ++u) {
        int unit = u * 256 + tid;    // [0,512): 128 h x 4 k-groups
        int hh = unit >> 2;
        int kg = unit & 3;
        bf16x8 v0, v1;
#pragma unroll
        for (int j = 0; j < 8; ++j) v0[j] = tile[(kg * 16 + j) * 132 + hh];
#pragma unroll
        for (int j = 0; j < 8; ++j) v1[j] = tile[(kg * 16 + 8 + j) * 132 + hh];
        __bf16* dst = wp + (size_t)(tg * 128 + hh) * 768 + k0 + kg * 16;
        *(bf16x8*)dst       = v0;
        *(bf16x8*)(dst + 8) = v1;
    }
}

// ---------------------------------------------------------------------------
// Phase 1: 256x256-tile GEMM over K=768 + fused gates.
// grid = 49 t x 4 mtile x 4 ntile (XCD-swizzled). 512 thr = 8 waves (4M x 2H).
// 2-phase K-step: {issue 24 ds_read (half0,half1) -> lgkmcnt(12) ->
// MFMA half0 (covers half1 LDS latency) -> lgkmcnt(0) -> s_barrier (buf free)
// -> STAGE ks+2 -> MFMA half1 (covers global loads) -> vmcnt(8) -> s_barrier}.
// Tile j always in buf j&1; 2 tiles in flight, never drain vmcnt to 0 mid-loop.
// ---------------------------------------------------------------------------
__global__ __launch_bounds__(512, 1) void phase1_kernel(
    const __bf16* __restrict__ ws,
    const float* __restrict__ c_h, const float* __restrict__ c_g_t,
    const float* __restrict__ bias, float* __restrict__ out)
{
    extern __shared__ __bf16 smem[];      // A: [0,32768) elems, B: [32768,65536)
    const __bf16* hb = ws + HB_OFF;
    const __bf16* pb = ws + PB_OFF;
    const __bf16* gb = ws + GB_OFF;
    const __bf16* wp = ws + WP_OFF;
    const __bf16* zp = ws + ZP_OFF;

    int bid = blockIdx.x;
    int swz = (bid & 7) * 98 + (bid >> 3);   // XCD swizzle, bijective (784 = 8*98)
    int t     = swz >> 4;
    int rem   = swz & 15;
    int mtile = rem >> 2, ntile = rem & 3;

    int tid  = threadIdx.x;
    int wave = tid >> 6, lane = tid & 63;
    int wm = wave >> 1, wh = wave & 1;
    int lg = lane >> 4, l16 = lane & 15;

    // staging per-lane constants: chunk = wave + it*8 covers rows R0 + it*64
    const int R0   = (wave << 3) + (lane >> 3);        // n in [0,64)
    const int k16s = ((lane & 7) ^ (R0 & 7)) << 3;     // pre-swizzled k elem off
    const int n    = R0;

    f32x4 acc[4][8];
    const f32x4 vzero = {0.f, 0.f, 0.f, 0.f};
#pragma unroll
    for (int mi = 0; mi < 4; ++mi)
#pragma unroll
        for (int g = 0; g < 8; ++g) acc[mi][g] = vzero;

    // fragment read bases (byte offsets into a buffer)
    int rbA[4], rsA[4], rbB[8], rsB[8];
#pragma unroll
    for (int mi = 0; mi < 4; ++mi) {
        int row = wm * 64 + mi * 16 + l16;
        rbA[mi] = row << 7;
        rsA[mi] = (row & 7) << 4;
    }
#pragma unroll
    for (int g = 0; g < 8; ++g) {
        int row = g * 32 + wh * 16 + l16;
        rbB[g] = row << 7;
        rsB[g] = (row & 7) << 4;
    }
    const int kb0 = lg << 4;

#define STAGE_A(BUF, KS) do {                                                   \
        int s_   = (KS) >> 1;                                                   \
        int koff = (((KS) & 1) << 6) + k16s;                                    \
        _Pragma("unroll")                                                       \
        for (int it = 0; it < 4; ++it) {                                        \
            int b_  = mtile * 4 + it;                                           \
            int bt_ = b_ * TD + t;                                              \
            const __bf16* src;                                                  \
            if (s_ == 0)      src = pb + ((bt_ * ND + n) << 7) + koff;          \
            else if (s_ == 1) src = (t > 0)    ? hb + (((bt_-1) * ND + n) << 7) + koff : zp; \
            else if (s_ == 2) src = hb + ((bt_ * ND + n) << 7) + koff;          \
            else if (s_ == 3) src = (t < TD-1) ? hb + (((bt_+1) * ND + n) << 7) + koff : zp; \
            else if (s_ == 4) src = (n > 0)    ? hb + ((bt_ * ND + n - 1) << 7) + koff : zp; \
            else              src = gb + (bt_ << 7) + koff;                     \
            __bf16* dst = smem + (BUF) * 16384 + (wave + it * 8) * 512;         \
            gload16(src, dst);                                                  \
        }                                                                       \
    } while (0)

#define STAGE_B(BUF, KS) do {                                                   \
        _Pragma("unroll")                                                       \
        for (int it = 0; it < 4; ++it) {                                        \
            int np = R0 + it * 64;                                              \
            int g_ = np >> 5, hc = np & 31;                                     \
            const __bf16* src = wp + (size_t)((t * 8 + g_) * 128 + ntile * 32 + hc) * 768 \
                                   + ((KS) << 6) + k16s;                        \
            __bf16* dst = smem + 32768 + (BUF) * 16384 + (wave + it * 8) * 512; \
            gload16(src, dst);                                                  \
        }                                                                       \
    } while (0)

    // prologue: tiles 0 and 1 in flight (8 loads each)
    STAGE_A(0, 0);
    STAGE_B(0, 0);
    STAGE_A(1, 1);
    STAGE_B(1, 1);
    asm volatile("s_waitcnt vmcnt(8)" ::: "memory");   // tile 0 landed
    __builtin_amdgcn_sched_barrier(0);
    __builtin_amdgcn_s_barrier();

    for (int ks = 0; ks < 12; ++ks) {
        const int buf = ks & 1;
        const char* Ab = (const char*)(smem + buf * 16384);
        const char* Bb = (const char*)(smem + 32768 + buf * 16384);

        bf16x8 af0[4], bf0[8], af1[4], bf1[8];
        // ---- half 0 reads (12 ds_read_b128)
#pragma unroll
        for (int mi = 0; mi < 4; ++mi)
            af0[mi] = *(const bf16x8*)(Ab + rbA[mi] + (kb0 ^ rsA[mi]));
#pragma unroll
        for (int g = 0; g < 8; ++g)
            bf0[g] = *(const bf16x8*)(Bb + rbB[g] + (kb0 ^ rsB[g]));
        __builtin_amdgcn_sched_barrier(0);             // pin issue order: half0 first
        // ---- half 1 reads (12 ds_read_b128)
#pragma unroll
        for (int mi = 0; mi < 4; ++mi)
            af1[mi] = *(const bf16x8*)(Ab + rbA[mi] + ((64 + kb0) ^ rsA[mi]));
#pragma unroll
        for (int g = 0; g < 8; ++g)
            bf1[g] = *(const bf16x8*)(Bb + rbB[g] + ((64 + kb0) ^ rsB[g]));

        asm volatile("s_waitcnt lgkmcnt(12)" ::: "memory");  // half0 landed, half1 in flight
        __builtin_amdgcn_sched_barrier(0);             // rule #18
        __builtin_amdgcn_s_setprio(1);
#pragma unroll
        for (int mi = 0; mi < 4; ++mi)
#pragma unroll
            for (int g = 0; g < 8; ++g)
                acc[mi][g] = __builtin_amdgcn_mfma_f32_16x16x32_bf16(af0[mi], bf0[g], acc[mi][g], 0, 0, 0);
        __builtin_amdgcn_s_setprio(0);

        asm volatile("s_waitcnt lgkmcnt(0)" ::: "memory");   // half1 landed
        __builtin_amdgcn_sched_barrier(0);
        __builtin_amdgcn_s_barrier();                  // all waves done reading buf

        // ---- overwrite freed buffer with tile ks+2 (stays in flight over MFMA)
        if (ks + 2 < 12) {
            STAGE_A(buf, ks + 2);
            STAGE_B(buf, ks + 2);
        }
        __builtin_amdgcn_sched_barrier(0);             // loads issued before MFMA half1

        __builtin_amdgcn_s_setprio(1);
#pragma unroll
        for (int mi = 0; mi < 4; ++mi)
#pragma unroll
            for (int g = 0; g < 8; ++g)
                acc[mi][g] = __builtin_amdgcn_mfma_f32_16x16x32_bf16(af1[mi], bf1[g], acc[mi][g], 0, 0, 0);
        __builtin_amdgcn_s_setprio(0);

        if (ks < 11) {
            if (ks + 2 < 12) {
                asm volatile("s_waitcnt vmcnt(8)" ::: "memory");  // tile ks+1 landed, ks+2 in flight
            } else {
                asm volatile("s_waitcnt vmcnt(0)" ::: "memory");  // tail: tile 11 landed
            }
            __builtin_amdgcn_sched_barrier(0);
            __builtin_amdgcn_s_barrier();
        }
    }

    // ---- epilogue: gates + cell update, in-register (8 gates per lane) ----
    const int hcol = ntile * 32 + wh * 16 + l16;
    float bv[8];
#pragma unroll
    for (int g = 0; g < 8; ++g) bv[g] = bias[(g * TD + t) * HD + hcol];

#pragma unroll
    for (int mi = 0; mi < 4; ++mi) {
#pragma unroll
        for (int r = 0; r < 4; ++r) {
            int RG = mtile * 256 + wm * 64 + mi * 16 + lg * 4 + r;
            int b  = RG >> 6, nn = RG & 63;
            int bt = b * TD + t;
            int base = ((bt * ND + nn) << 7) + hcol;
            float pre[8];
#pragma unroll
            for (int g = 0; g < 8; ++g) pre[g] = acc[mi][g][r] + bv[g];
            float i_  = sigf(pre[0]);
            float flt = sigf(pre[1]);
            float fft = sigf(pre[2]);
            float frt = sigf(pre[3]);
            float fs  = sigf(pre[4]);
            float gn  = sigf(pre[5]);
            float on  = sigf(pre[6]);
            float cn  = tanhf_fast(pre[7]);
            float ccur = c_h[base];
            float ctb  = (t > 0)      ? c_h[base - ND * HD] : 0.f;
            float cta  = (t < TD - 1) ? c_h[base + ND * HD] : 0.f;
            float csb  = (nn > 0)     ? c_h[base - HD]      : 0.f;
            float cg   = c_g_t[(bt << 7) + hcol];
            float cnew = i_ * cn + flt * ctb + fft * ccur + frt * cta + fs * csb + gn * cg;
            float hnew = on * tanhf_fast(cnew);
            out[OUT_H  + base] = hnew;
            out[OUT_CH + base] = cnew;
        }
    }
#undef STAGE_A
#undef STAGE_B
}

// ---------------------------------------------------------------------------
// Phase 2: per (b,t) workgroup.  f_gtf GEMM + bone-mean reduction + tiny dots.
// ---------------------------------------------------------------------------
__global__ __launch_bounds__(256, 2) void phase2_kernel(
    const float* __restrict__ g_t, const float* __restrict__ c_g_t,
    const float* __restrict__ Wg,  const float* __restrict__ Zg,
    const float* __restrict__ bg,  float* __restrict__ out)
{
    __shared__ __bf16 A2[64 * KPAD];
    __shared__ __bf16 Wb[128 * KPAD];
    __shared__ float  gts[128];
    __shared__ float  hm[128];
    __shared__ float  dots[5][128];
    __shared__ float  ps[2][128];
    __shared__ float  red[4][128];

    const int bid  = blockIdx.x;
    const int t    = bid >> 4;
    const int b    = bid & 15;
    const int tid  = threadIdx.x;
    const int wv   = tid >> 6;
    const int lane = tid & 63;
    const int lg   = lane >> 4;
    const int l16  = lane & 15;
    const int bt   = b * TD + t;

    const float* hn  = out + OUT_H;
    const float* chn = out + OUT_CH;

#pragma unroll
    for (int j = 0; j < 8; ++j) {
        int fid = j * 256 + tid;
        int r   = fid >> 5;
        int k   = (fid & 31) << 2;
        f32x4 v = *(const f32x4*)(hn + ((bt * ND + r) << 7) + k);
        bf16x4 w;
        w[0] = (__bf16)v[0]; w[1] = (__bf16)v[1]; w[2] = (__bf16)v[2]; w[3] = (__bf16)v[3];
        *(bf16x4*)(A2 + r * KPAD + k) = w;
    }
    if (tid < 128) gts[tid] = g_t[(bt << 7) + tid];
    __syncthreads();

    {
        int c = tid & 127, half = tid >> 7;
        float sum_ = 0.f;
        for (int r2 = 0; r2 < 32; ++r2) sum_ += (float)A2[(half * 32 + r2) * KPAD + c];
        ps[half][c] = sum_;
    }
    __syncthreads();
    if (tid < 128) hm[tid] = (ps[0][tid] + ps[1][tid]) * (1.f / 64.f);

    for (int m = 0; m < 5; ++m) {
        const float* M = (m < 3) ? (Zg + ((size_t)(m * TD + t) << 14))
                                 : (Wg + ((size_t)((m - 2) * TD + t) << 14));
        const bool use_hm = (m >= 3);
        __syncthreads();
#pragma unroll
        for (int j = 0; j < 16; ++j) {
            int fid = j * 256 + tid;
            int k   = fid >> 5;
            int c4  = (fid & 31) << 2;
            f32x4 v = *(const f32x4*)(M + (k << 7) + c4);
            bf16x4 w;
            w[0] = (__bf16)v[0]; w[1] = (__bf16)v[1]; w[2] = (__bf16)v[2]; w[3] = (__bf16)v[3];
            *(bf16x4*)(Wb + (k << 7) + c4) = w;
        }
        __syncthreads();
        {
            int c = tid & 127, half = tid >> 7;
            const float* vec = use_hm ? hm : gts;
            float sum_ = 0.f;
            for (int k = half * 64; k < half * 64 + 64; ++k)
                sum_ += vec[k] * (float)Wb[(k << 7) + c];
            ps[half][c] = sum_;
        }
        __syncthreads();
        if (tid < 128) dots[m][tid] = ps[0][tid] + ps[1][tid];
    }

    {
        const float* M = Wg + ((size_t)t << 14);
        __syncthreads();
#pragma unroll
        for (int j = 0; j < 16; ++j) {
            int fid = j * 256 + tid;
            int k   = fid >> 5;
            int q   = fid & 31;
            f32x4 v = *(const f32x4*)(M + (k << 7) + q * 4);
            int cb = q * 4;
            Wb[(cb + 0) * KPAD + k] = (__bf16)v[0];
            Wb[(cb + 1) * KPAD + k] = (__bf16)v[1];
            Wb[(cb + 2) * KPAD + k] = (__bf16)v[2];
            Wb[(cb + 3) * KPAD + k] = (__bf16)v[3];
        }
        __syncthreads();
    }

    f32x4 acc[8];
    const f32x4 vzero = {0.f, 0.f, 0.f, 0.f};
#pragma unroll
    for (int cf = 0; cf < 8; ++cf) acc[cf] = vzero;
#pragma unroll
    for (int ks = 0; ks < 4; ++ks) {
        int kb = ks * 32 + lg * 8;
        bf16x8 a = *(const bf16x8*)(A2 + (wv * 16 + l16) * KPAD + kb);
#pragma unroll
        for (int cf = 0; cf < 8; ++cf) {
            bf16x8 bfr = *(const bf16x8*)(Wb + (cf * 16 + l16) * KPAD + kb);
            acc[cf] = __builtin_amdgcn_mfma_f32_16x16x32_bf16(a, bfr, acc[cf], 0, 0, 0);
        }
    }

#pragma unroll
    for (int cf = 0; cf < 8; ++cf) {
        int col = cf * 16 + l16;
        float z = dots[0][col] + bg[(0 * TD + t) * HD + col];
        float macc = 0.f;
#pragma unroll
        for (int r = 0; r < 4; ++r) {
            int row = wv * 16 + lg * 4 + r;
            float f  = sigf(acc[cf][r] + z);
            float cv = chn[((bt * ND + row) << 7) + col];
            macc += f * cv;
        }
        macc += __shfl_xor(macc, 16, 64);
        macc += __shfl_xor(macc, 32, 64);
        if (lane < 16) red[wv][col] = macc;
    }
    __syncthreads();
    if (tid < 128) {
        int c = tid;
        float Mn  = (red[0][c] + red[1][c] + red[2][c] + red[3][c]) * (1.f / 64.f);
        float g_g = sigf(dots[3][c] + dots[1][c] + bg[(1 * TD + t) * HD + c]);
        float o_g = sigf(dots[4][c] + dots[2][c] + bg[(2 * TD + t) * HD + c]);
        float cgt = c_g_t[(bt << 7) + c];
        float cgn = Mn + g_g * cgt;
        float gnw = tanhf_fast(cgn) * o_g;
        out[OUT_G  + (bt << 7) + c] = gnw;
        out[OUT_CG + (bt << 7) + c] = cgn;
    }
}

extern "C" void kernel_launch(void* const* d_in, const int* in_sizes, int n_in,
                              void* d_out, int out_size, void* d_ws, size_t ws_size,
                              hipStream_t stream) {
    const float* h     = (const float*)d_in[0];
    const float* c_h   = (const float*)d_in[1];
    const float* p     = (const float*)d_in[2];
    const float* g_t   = (const float*)d_in[3];
    const float* c_g_t = (const float*)d_in[4];
    const float* U     = (const float*)d_in[5];
    const float* Wt    = (const float*)d_in[6];
    const float* Ws    = (const float*)d_in[7];
    const float* Zt    = (const float*)d_in[8];
    const float* b     = (const float*)d_in[9];
    const float* Wg    = (const float*)d_in[10];
    const float* Zg    = (const float*)d_in[11];
    const float* bg    = (const float*)d_in[12];
    float* out = (float*)d_out;
    __bf16* ws = (__bf16*)d_ws;

    // prep: 2*1605632 + 25088 + 512 = 3,236,864 units -> 12644 blocks
    prep_acts<<<12644, 256, 0, stream>>>(h, p, g_t, ws);
    prep_w<<<TD * 8 * 12, 256, 0, stream>>>(U, Wt, Ws, Zt, ws + WP_OFF);

    (void)hipFuncSetAttribute(reinterpret_cast<const void*>(phase1_kernel),
                              hipFuncAttributeMaxDynamicSharedMemorySize, LDS1_BYTES);
    phase1_kernel<<<TD * 16, 512, LDS1_BYTES, stream>>>(ws, c_h, c_g_t, b, out);
    phase2_kernel<<<TD * BD, 256, 0, stream>>>(g_t, c_g_t, Wg, Zg, bg, out);
}

// Round 6
// 253.284 us; speedup vs baseline: 1.1984x; 1.1389x over previous
//
#include <hip/hip_runtime.h>
#include <hip/hip_bf16.h>

#define TD 49
#define BD 16
#define ND 64
#define HD 128

typedef float  f32x4  __attribute__((ext_vector_type(4)));
typedef __bf16 bf16x8 __attribute__((ext_vector_type(8)));
typedef __bf16 bf16x4 __attribute__((ext_vector_type(4)));

// ---------------- workspace layout (bf16 element offsets) ----------------
#define WP_OFF   0u
#define WP_ELEMS 38535168u           // 49*8*128*768  : W' [t][g][h][k] bf16
#define HB_OFF   38535168u           // h  bf16 [B,T,N,H]
#define ACT_ELEMS 6422528u           // 16*49*64*128
#define PB_OFF   44957696u           // p  bf16
#define GB_OFF   51380224u           // g_t bf16 [B,T,H]
#define GT_ELEMS 100352u
#define ZP_OFF   51480576u           // 2048 bf16 zeros (pad source page)
// total = 51482624 elems = 102,965,248 bytes

#define OUT_H    0
#define OUT_CH   6422528
#define OUT_G    12845056
#define OUT_CG   12945408

#define KPAD 136
#define LDS1_BYTES 65536             // A[2][128][64] + B[2][128][64] bf16 -> 2 blocks/CU

__device__ __forceinline__ float sigf(float x) {
    return 1.0f / (1.0f + exp2f(-1.442695041f * x));
}
__device__ __forceinline__ float tanhf_fast(float x) {
    x = fminf(fmaxf(x, -20.f), 20.f);
    float e = exp2f(2.885390082f * x);
    return (e - 1.f) / (e + 1.f);
}
__device__ __forceinline__ void gload16(const void* g, void* l) {
    __builtin_amdgcn_global_load_lds((const __attribute__((address_space(1))) void*)g,
                                     (__attribute__((address_space(3))) void*)l, 16, 0, 0);
}

// ---------------------------------------------------------------------------
// prep_acts: cast h, p, g_t f32 -> bf16 into ws; fill zero page.
// ---------------------------------------------------------------------------
__global__ void prep_acts(const float* __restrict__ h, const float* __restrict__ p,
                          const float* __restrict__ g, __bf16* __restrict__ ws)
{
    unsigned i = blockIdx.x * 256u + threadIdx.x;
    const unsigned HU = ACT_ELEMS / 4u, GU = GT_ELEMS / 4u;
    const float* src;
    unsigned dst;
    if (i < HU)                 { src = h + (size_t)i * 4;          dst = HB_OFF + i * 4; }
    else if (i < 2u*HU)         { unsigned j = i - HU;   src = p + (size_t)j * 4; dst = PB_OFF + j * 4; }
    else if (i < 2u*HU + GU)    { unsigned j = i - 2u*HU; src = g + (size_t)j * 4; dst = GB_OFF + j * 4; }
    else if (i < 2u*HU + GU + 512u) {
        unsigned j = i - 2u*HU - GU;
        bf16x4 z = {};
        *(bf16x4*)(ws + ZP_OFF + j * 4) = z;
        return;
    } else return;
    f32x4 v = *(const f32x4*)src;
    bf16x4 w;
    w[0] = (__bf16)v[0]; w[1] = (__bf16)v[1]; w[2] = (__bf16)v[2]; w[3] = (__bf16)v[3];
    *(bf16x4*)(ws + dst) = w;
}

// ---------------------------------------------------------------------------
// prep_w: transpose+cast weights into W'[t][g][h=128][k=768] bf16,
//         k-order = [U | Wt0 | Wt1 | Wt2 | Ws | Zt].
// grid = 49*8*12 (one 64-k chunk per block).
// ---------------------------------------------------------------------------
__global__ __launch_bounds__(256) void prep_w(
    const float* __restrict__ U, const float* __restrict__ Wt,
    const float* __restrict__ Ws, const float* __restrict__ Zt,
    __bf16* __restrict__ wp)
{
    __shared__ __bf16 tile[64 * 132];
    int bid = blockIdx.x;
    int tg  = bid / 12;              // t*8+g
    int c   = bid % 12;
    int t   = tg >> 3, g = tg & 7;
    int gt  = g * TD + t;
    int tid = threadIdx.x;
    int k0  = c * 64;

#pragma unroll
    for (int u = 0; u < 8; ++u) {
        int unit = u * 256 + tid;    // [0,2048): 64 k x 32 f32x4
        int kk = unit >> 5;
        int h4 = (unit & 31) << 2;
        int k  = k0 + kk;
        const float* src;
        if (k < 128)      src = U  + ((size_t)(gt * 128 + k)       << 7);
        else if (k < 512) src = Wt + ((size_t)(gt * 384 + (k-128)) << 7);
        else if (k < 640) src = Ws + ((size_t)(gt * 128 + (k-512)) << 7);
        else              src = Zt + ((size_t)(gt * 128 + (k-640)) << 7);
        f32x4 v = *(const f32x4*)(src + h4);
        bf16x4 w;
        w[0] = (__bf16)v[0]; w[1] = (__bf16)v[1]; w[2] = (__bf16)v[2]; w[3] = (__bf16)v[3];
        *(bf16x4*)(tile + kk * 132 + h4) = w;
    }
    __syncthreads();
#pragma unroll
    for (int u = 0; u < 2; ++u) {
        int unit = u * 256 + tid;    // [0,512): 128 h x 4 k-groups
        int hh = unit >> 2;
        int kg = unit & 3;
        bf16x8 v0, v1;
#pragma unroll
        for (int j = 0; j < 8; ++j) v0[j] = tile[(kg * 16 + j) * 132 + hh];
#pragma unroll
        for (int j = 0; j < 8; ++j) v1[j] = tile[(kg * 16 + 8 + j) * 132 + hh];
        __bf16* dst = wp + (size_t)(tg * 128 + hh) * 768 + k0 + kg * 16;
        *(bf16x8*)dst       = v0;
        *(bf16x8*)(dst + 8) = v1;
    }
}

// ---------------------------------------------------------------------------
// Phase 1: m97-structure GEMM. 128x128 tile (M=128, N = 8 gates x 16 hcols),
// BK=64, K=768 (12 steps). 256 thr = 4 waves, wave owns 32 rows x all 8 gates
// (in-register gate epilogue). LDS 64 KB dbuf -> 2 blocks/CU; plain
// __syncthreads loop, stage-ahead-1 global_load_lds, XOR-swizzled LDS.
// grid = 49 t x 8 mtile x 8 ntile = 3136, XCD-swizzled (3136 = 8*392).
// ---------------------------------------------------------------------------
__global__ __launch_bounds__(256, 2) void phase1_kernel(
    const __bf16* __restrict__ ws,
    const float* __restrict__ c_h, const float* __restrict__ c_g_t,
    const float* __restrict__ bias, float* __restrict__ out)
{
    extern __shared__ __bf16 smem[];      // A bufs: [0,16384) elems; B bufs: [16384,32768)
    const __bf16* hb = ws + HB_OFF;
    const __bf16* pb = ws + PB_OFF;
    const __bf16* gb = ws + GB_OFF;
    const __bf16* wp = ws + WP_OFF;
    const __bf16* zp = ws + ZP_OFF;

    int bid = blockIdx.x;
    int swz = (bid & 7) * 392 + (bid >> 3);  // XCD swizzle, bijective (3136 = 8*392)
    int t     = swz >> 6;
    int rem   = swz & 63;
    int mtile = rem >> 3, ntile = rem & 7;

    int tid  = threadIdx.x;
    int wave = tid >> 6, lane = tid & 63;    // wave = wm in [0,4)
    int lg = lane >> 4, l16 = lane & 15;

    const int ls   = lane >> 3;              // row-in-chunk [0,8)
    const int k16s = ((lane & 7) ^ ls) << 3; // pre-swizzled k elem offset (R&7 == ls)

    f32x4 acc[2][8];
    const f32x4 vzero = {0.f, 0.f, 0.f, 0.f};
#pragma unroll
    for (int mi = 0; mi < 2; ++mi)
#pragma unroll
        for (int g = 0; g < 8; ++g) acc[mi][g] = vzero;

    // fragment read bases (byte offsets into a 128x64 bf16 buffer; row = 128 B)
    int rbA[2], rsA[2], rbB[8], rsB[8];
#pragma unroll
    for (int mi = 0; mi < 2; ++mi) {
        int row = wave * 32 + mi * 16 + l16;
        rbA[mi] = row << 7;
        rsA[mi] = (row & 7) << 4;
    }
#pragma unroll
    for (int g = 0; g < 8; ++g) {
        int row = g * 16 + l16;
        rbB[g] = row << 7;
        rsB[g] = (l16 & 7) << 4;
    }
    const int kb0 = lg << 4;

    // STAGE: A tile rows R = chunk*8+ls (R in [0,128)); global row mtile*128+R
    //        B tile rows R = g*16+hc;   chunk = it*4 + wave (16 chunks of 8 rows)
#define STAGE(BUF, KS) do {                                                     \
        int s_   = (KS) >> 1;                                                   \
        int koff = (((KS) & 1) << 6) + k16s;                                    \
        _Pragma("unroll")                                                       \
        for (int it = 0; it < 4; ++it) {                                        \
            int chunk = it * 4 + wave;                                          \
            int R   = chunk * 8 + ls;                                           \
            int b_  = mtile * 2 + (R >> 6);                                     \
            int n_  = R & 63;                                                   \
            int bt_ = b_ * TD + t;                                              \
            const __bf16* srcA;                                                 \
            if (s_ == 0)      srcA = pb + ((bt_ * ND + n_) << 7) + koff;        \
            else if (s_ == 1) srcA = (t > 0)    ? hb + (((bt_-1) * ND + n_) << 7) + koff : zp; \
            else if (s_ == 2) srcA = hb + ((bt_ * ND + n_) << 7) + koff;        \
            else if (s_ == 3) srcA = (t < TD-1) ? hb + (((bt_+1) * ND + n_) << 7) + koff : zp; \
            else if (s_ == 4) srcA = (n_ > 0)   ? hb + ((bt_ * ND + n_ - 1) << 7) + koff : zp; \
            else              srcA = gb + (bt_ << 7) + koff;                    \
            gload16(srcA, smem + (BUF) * 8192 + chunk * 512);                   \
            int g_ = R >> 4, hc = R & 15;                                       \
            const __bf16* srcB = wp + (size_t)((t * 8 + g_) * 128 + ntile * 16 + hc) * 768 \
                                    + ((KS) << 6) + k16s;                       \
            gload16(srcB, smem + 16384 + (BUF) * 8192 + chunk * 512);           \
        }                                                                       \
    } while (0)

    STAGE(0, 0);
    __syncthreads();

    int buf = 0;
    for (int ks = 0; ks < 12; ++ks) {
        if (ks < 11) STAGE(buf ^ 1, ks + 1);
        const char* Ab = (const char*)(smem + buf * 8192);
        const char* Bb = (const char*)(smem + 16384 + buf * 8192);
#pragma unroll
        for (int ks32 = 0; ks32 < 2; ++ks32) {
            bf16x8 af[2], bfr[8];
#pragma unroll
            for (int mi = 0; mi < 2; ++mi)
                af[mi] = *(const bf16x8*)(Ab + rbA[mi] + (((ks32 << 6) + kb0) ^ rsA[mi]));
#pragma unroll
            for (int g = 0; g < 8; ++g)
                bfr[g] = *(const bf16x8*)(Bb + rbB[g] + (((ks32 << 6) + kb0) ^ rsB[g]));
#pragma unroll
            for (int mi = 0; mi < 2; ++mi)
#pragma unroll
                for (int g = 0; g < 8; ++g)
                    acc[mi][g] = __builtin_amdgcn_mfma_f32_16x16x32_bf16(af[mi], bfr[g], acc[mi][g], 0, 0, 0);
        }
        __syncthreads();
        buf ^= 1;
    }

    // ---- epilogue: gates + cell update, in-register (8 gates per lane) ----
    const int hcol = ntile * 16 + l16;
    float bv[8];
#pragma unroll
    for (int g = 0; g < 8; ++g) bv[g] = bias[(g * TD + t) * HD + hcol];

#pragma unroll
    for (int mi = 0; mi < 2; ++mi) {
#pragma unroll
        for (int r = 0; r < 4; ++r) {
            int RG = mtile * 128 + wave * 32 + mi * 16 + lg * 4 + r;
            int b  = RG >> 6, nn = RG & 63;
            int bt = b * TD + t;
            int base = ((bt * ND + nn) << 7) + hcol;
            float pre[8];
#pragma unroll
            for (int g = 0; g < 8; ++g) pre[g] = acc[mi][g][r] + bv[g];
            float i_  = sigf(pre[0]);
            float flt = sigf(pre[1]);
            float fft = sigf(pre[2]);
            float frt = sigf(pre[3]);
            float fs  = sigf(pre[4]);
            float gn  = sigf(pre[5]);
            float on  = sigf(pre[6]);
            float cn  = tanhf_fast(pre[7]);
            float ccur = c_h[base];
            float ctb  = (t > 0)      ? c_h[base - ND * HD] : 0.f;
            float cta  = (t < TD - 1) ? c_h[base + ND * HD] : 0.f;
            float csb  = (nn > 0)     ? c_h[base - HD]      : 0.f;
            float cg   = c_g_t[(bt << 7) + hcol];
            float cnew = i_ * cn + flt * ctb + fft * ccur + frt * cta + fs * csb + gn * cg;
            float hnew = on * tanhf_fast(cnew);
            out[OUT_H  + base] = hnew;
            out[OUT_CH + base] = cnew;
        }
    }
#undef STAGE
}

// ---------------------------------------------------------------------------
// Phase 2: per (b,t) workgroup.  f_gtf GEMM + bone-mean reduction + tiny dots.
// ---------------------------------------------------------------------------
__global__ __launch_bounds__(256, 2) void phase2_kernel(
    const float* __restrict__ g_t, const float* __restrict__ c_g_t,
    const float* __restrict__ Wg,  const float* __restrict__ Zg,
    const float* __restrict__ bg,  float* __restrict__ out)
{
    __shared__ __bf16 A2[64 * KPAD];
    __shared__ __bf16 Wb[128 * KPAD];
    __shared__ float  gts[128];
    __shared__ float  hm[128];
    __shared__ float  dots[5][128];
    __shared__ float  ps[2][128];
    __shared__ float  red[4][128];

    const int bid  = blockIdx.x;
    const int t    = bid >> 4;
    const int b    = bid & 15;
    const int tid  = threadIdx.x;
    const int wv   = tid >> 6;
    const int lane = tid & 63;
    const int lg   = lane >> 4;
    const int l16  = lane & 15;
    const int bt   = b * TD + t;

    const float* hn  = out + OUT_H;
    const float* chn = out + OUT_CH;

#pragma unroll
    for (int j = 0; j < 8; ++j) {
        int fid = j * 256 + tid;
        int r   = fid >> 5;
        int k   = (fid & 31) << 2;
        f32x4 v = *(const f32x4*)(hn + ((bt * ND + r) << 7) + k);
        bf16x4 w;
        w[0] = (__bf16)v[0]; w[1] = (__bf16)v[1]; w[2] = (__bf16)v[2]; w[3] = (__bf16)v[3];
        *(bf16x4*)(A2 + r * KPAD + k) = w;
    }
    if (tid < 128) gts[tid] = g_t[(bt << 7) + tid];
    __syncthreads();

    {
        int c = tid & 127, half = tid >> 7;
        float sum_ = 0.f;
        for (int r2 = 0; r2 < 32; ++r2) sum_ += (float)A2[(half * 32 + r2) * KPAD + c];
        ps[half][c] = sum_;
    }
    __syncthreads();
    if (tid < 128) hm[tid] = (ps[0][tid] + ps[1][tid]) * (1.f / 64.f);

    for (int m = 0; m < 5; ++m) {
        const float* M = (m < 3) ? (Zg + ((size_t)(m * TD + t) << 14))
                                 : (Wg + ((size_t)((m - 2) * TD + t) << 14));
        const bool use_hm = (m >= 3);
        __syncthreads();
#pragma unroll
        for (int j = 0; j < 16; ++j) {
            int fid = j * 256 + tid;
            int k   = fid >> 5;
            int c4  = (fid & 31) << 2;
            f32x4 v = *(const f32x4*)(M + (k << 7) + c4);
            bf16x4 w;
            w[0] = (__bf16)v[0]; w[1] = (__bf16)v[1]; w[2] = (__bf16)v[2]; w[3] = (__bf16)v[3];
            *(bf16x4*)(Wb + (k << 7) + c4) = w;
        }
        __syncthreads();
        {
            int c = tid & 127, half = tid >> 7;
            const float* vec = use_hm ? hm : gts;
            float sum_ = 0.f;
            for (int k = half * 64; k < half * 64 + 64; ++k)
                sum_ += vec[k] * (float)Wb[(k << 7) + c];
            ps[half][c] = sum_;
        }
        __syncthreads();
        if (tid < 128) dots[m][tid] = ps[0][tid] + ps[1][tid];
    }

    {
        const float* M = Wg + ((size_t)t << 14);
        __syncthreads();
#pragma unroll
        for (int j = 0; j < 16; ++j) {
            int fid = j * 256 + tid;
            int k   = fid >> 5;
            int q   = fid & 31;
            f32x4 v = *(const f32x4*)(M + (k << 7) + q * 4);
            int cb = q * 4;
            Wb[(cb + 0) * KPAD + k] = (__bf16)v[0];
            Wb[(cb + 1) * KPAD + k] = (__bf16)v[1];
            Wb[(cb + 2) * KPAD + k] = (__bf16)v[2];
            Wb[(cb + 3) * KPAD + k] = (__bf16)v[3];
        }
        __syncthreads();
    }

    f32x4 acc[8];
    const f32x4 vzero = {0.f, 0.f, 0.f, 0.f};
#pragma unroll
    for (int cf = 0; cf < 8; ++cf) acc[cf] = vzero;
#pragma unroll
    for (int ks = 0; ks < 4; ++ks) {
        int kb = ks * 32 + lg * 8;
        bf16x8 a = *(const bf16x8*)(A2 + (wv * 16 + l16) * KPAD + kb);
#pragma unroll
        for (int cf = 0; cf < 8; ++cf) {
            bf16x8 bfr = *(const bf16x8*)(Wb + (cf * 16 + l16) * KPAD + kb);
            acc[cf] = __builtin_amdgcn_mfma_f32_16x16x32_bf16(a, bfr, acc[cf], 0, 0, 0);
        }
    }

#pragma unroll
    for (int cf = 0; cf < 8; ++cf) {
        int col = cf * 16 + l16;
        float z = dots[0][col] + bg[(0 * TD + t) * HD + col];
        float macc = 0.f;
#pragma unroll
        for (int r = 0; r < 4; ++r) {
            int row = wv * 16 + lg * 4 + r;
            float f  = sigf(acc[cf][r] + z);
            float cv = chn[((bt * ND + row) << 7) + col];
            macc += f * cv;
        }
        macc += __shfl_xor(macc, 16, 64);
        macc += __shfl_xor(macc, 32, 64);
        if (lane < 16) red[wv][col] = macc;
    }
    __syncthreads();
    if (tid < 128) {
        int c = tid;
        float Mn  = (red[0][c] + red[1][c] + red[2][c] + red[3][c]) * (1.f / 64.f);
        float g_g = sigf(dots[3][c] + dots[1][c] + bg[(1 * TD + t) * HD + c]);
        float o_g = sigf(dots[4][c] + dots[2][c] + bg[(2 * TD + t) * HD + c]);
        float cgt = c_g_t[(bt << 7) + c];
        float cgn = Mn + g_g * cgt;
        float gnw = tanhf_fast(cgn) * o_g;
        out[OUT_G  + (bt << 7) + c] = gnw;
        out[OUT_CG + (bt << 7) + c] = cgn;
    }
}

extern "C" void kernel_launch(void* const* d_in, const int* in_sizes, int n_in,
                              void* d_out, int out_size, void* d_ws, size_t ws_size,
                              hipStream_t stream) {
    const float* h     = (const float*)d_in[0];
    const float* c_h   = (const float*)d_in[1];
    const float* p     = (const float*)d_in[2];
    const float* g_t   = (const float*)d_in[3];
    const float* c_g_t = (const float*)d_in[4];
    const float* U     = (const float*)d_in[5];
    const float* Wt    = (const float*)d_in[6];
    const float* Ws    = (const float*)d_in[7];
    const float* Zt    = (const float*)d_in[8];
    const float* b     = (const float*)d_in[9];
    const float* Wg    = (const float*)d_in[10];
    const float* Zg    = (const float*)d_in[11];
    const float* bg    = (const float*)d_in[12];
    float* out = (float*)d_out;
    __bf16* ws = (__bf16*)d_ws;

    // prep: 2*1605632 + 25088 + 512 = 3,236,864 units -> 12644 blocks
    prep_acts<<<12644, 256, 0, stream>>>(h, p, g_t, ws);
    prep_w<<<TD * 8 * 12, 256, 0, stream>>>(U, Wt, Ws, Zt, ws + WP_OFF);

    (void)hipFuncSetAttribute(reinterpret_cast<const void*>(phase1_kernel),
                              hipFuncAttributeMaxDynamicSharedMemorySize, LDS1_BYTES);
    phase1_kernel<<<TD * 64, 256, LDS1_BYTES, stream>>>(ws, c_h, c_g_t, b, out);
    phase2_kernel<<<TD * BD, 256, 0, stream>>>(g_t, c_g_t, Wg, Zg, bg, out);
}

// Round 7
// 234.913 us; speedup vs baseline: 1.2921x; 1.0782x over previous
//
#include <hip/hip_runtime.h>
#include <hip/hip_bf16.h>

#define TD 49
#define BD 16
#define ND 64
#define HD 128

typedef float  f32x4  __attribute__((ext_vector_type(4)));
typedef __bf16 bf16x8 __attribute__((ext_vector_type(8)));
typedef __bf16 bf16x4 __attribute__((ext_vector_type(4)));

// ---------------- workspace layout (bf16 element offsets) ----------------
#define WP_OFF   0u
#define HB_OFF   38535168u           // h  bf16 [B,T,N,H]
#define ACT_ELEMS 6422528u
#define PB_OFF   44957696u           // p  bf16
#define GB_OFF   51380224u           // g_t bf16 [B,T,H]
#define GT_ELEMS 100352u
#define ZP_OFF   51480576u           // 2048 bf16 zeros (pad source page)
// total = 51482624 elems = 102,965,248 bytes (unchanged from R3-R6)

#define OUT_H    0
#define OUT_CH   6422528
#define OUT_G    12845056
#define OUT_CG   12945408

#define KPAD 136
#define LDS1_BYTES 65536             // 4 slots x (A 8KB + B 8KB) -> 2 blocks/CU
#define LDS2_BYTES 118784            // A2 69632 + Wb 34816 + gts 2048 + hm 2048 + dts 10240

__device__ __forceinline__ float sigf(float x) {
    return 1.0f / (1.0f + exp2f(-1.442695041f * x));
}
__device__ __forceinline__ float tanhf_fast(float x) {
    x = fminf(fmaxf(x, -20.f), 20.f);
    float e = exp2f(2.885390082f * x);
    return (e - 1.f) / (e + 1.f);
}
__device__ __forceinline__ void gload16(const void* g, void* l) {
    __builtin_amdgcn_global_load_lds((const __attribute__((address_space(1))) void*)g,
                                     (__attribute__((address_space(3))) void*)l, 16, 0, 0);
}

// ---------------------------------------------------------------------------
// prep_acts: cast h, p, g_t f32 -> bf16 into ws; fill zero page.
// ---------------------------------------------------------------------------
__global__ void prep_acts(const float* __restrict__ h, const float* __restrict__ p,
                          const float* __restrict__ g, __bf16* __restrict__ ws)
{
    unsigned i = blockIdx.x * 256u + threadIdx.x;
    const unsigned HU = ACT_ELEMS / 4u, GU = GT_ELEMS / 4u;
    const float* src;
    unsigned dst;
    if (i < HU)                 { src = h + (size_t)i * 4;          dst = HB_OFF + i * 4; }
    else if (i < 2u*HU)         { unsigned j = i - HU;   src = p + (size_t)j * 4; dst = PB_OFF + j * 4; }
    else if (i < 2u*HU + GU)    { unsigned j = i - 2u*HU; src = g + (size_t)j * 4; dst = GB_OFF + j * 4; }
    else if (i < 2u*HU + GU + 512u) {
        unsigned j = i - 2u*HU - GU;
        bf16x4 z = {};
        *(bf16x4*)(ws + ZP_OFF + j * 4) = z;
        return;
    } else return;
    f32x4 v = *(const f32x4*)src;
    bf16x4 w;
    w[0] = (__bf16)v[0]; w[1] = (__bf16)v[1]; w[2] = (__bf16)v[2]; w[3] = (__bf16)v[3];
    *(bf16x4*)(ws + dst) = w;
}

// ---------------------------------------------------------------------------
// prep_w: transpose+cast weights into W'[t][g][h=128][k=768] bf16.
// ---------------------------------------------------------------------------
__global__ __launch_bounds__(256) void prep_w(
    const float* __restrict__ U, const float* __restrict__ Wt,
    const float* __restrict__ Ws, const float* __restrict__ Zt,
    __bf16* __restrict__ wp)
{
    __shared__ __bf16 tile[64 * 132];
    int bid = blockIdx.x;
    int tg  = bid / 12;
    int c   = bid % 12;
    int t   = tg >> 3, g = tg & 7;
    int gt  = g * TD + t;
    int tid = threadIdx.x;
    int k0  = c * 64;

#pragma unroll
    for (int u = 0; u < 8; ++u) {
        int unit = u * 256 + tid;
        int kk = unit >> 5;
        int h4 = (unit & 31) << 2;
        int k  = k0 + kk;
        const float* src;
        if (k < 128)      src = U  + ((size_t)(gt * 128 + k)       << 7);
        else if (k < 512) src = Wt + ((size_t)(gt * 384 + (k-128)) << 7);
        else if (k < 640) src = Ws + ((size_t)(gt * 128 + (k-512)) << 7);
        else              src = Zt + ((size_t)(gt * 128 + (k-640)) << 7);
        f32x4 v = *(const f32x4*)(src + h4);
        bf16x4 w;
        w[0] = (__bf16)v[0]; w[1] = (__bf16)v[1]; w[2] = (__bf16)v[2]; w[3] = (__bf16)v[3];
        *(bf16x4*)(tile + kk * 132 + h4) = w;
    }
    __syncthreads();
#pragma unroll
    for (int u = 0; u < 2; ++u) {
        int unit = u * 256 + tid;
        int hh = unit >> 2;
        int kg = unit & 3;
        bf16x8 v0, v1;
#pragma unroll
        for (int j = 0; j < 8; ++j) v0[j] = tile[(kg * 16 + j) * 132 + hh];
#pragma unroll
        for (int j = 0; j < 8; ++j) v1[j] = tile[(kg * 16 + 8 + j) * 132 + hh];
        __bf16* dst = wp + (size_t)(tg * 128 + hh) * 768 + k0 + kg * 16;
        *(bf16x8*)dst       = v0;
        *(bf16x8*)(dst + 8) = v1;
    }
}

// ---------------------------------------------------------------------------
// Phase 1: 128x128 tile, BK=32, 24 K-tiles, 4 LDS slots, depth-3 prefetch,
// counted vmcnt(8) + raw s_barrier (never drains mid-loop). 4 waves, wave =
// 32 rows x all 8 gates x 16 hcols (in-register gate epilogue).
// Slot math: step ks stages tile ks+3 into slot (ks+3)&3 = (ks-1)&3, which all
// waves finished reading at the end-of-step-(ks-1) barrier. vmcnt(8) at step
// end => tile ks+1 landed (tiles ks+2, ks+3 = 8 loads stay in flight).
// ---------------------------------------------------------------------------
__global__ __launch_bounds__(256, 2) void phase1_kernel(
    const __bf16* __restrict__ ws,
    const float* __restrict__ c_h, const float* __restrict__ c_g_t,
    const float* __restrict__ bias, float* __restrict__ out)
{
    extern __shared__ __bf16 smem[];     // A slots: elems [0,16384); B: [16384,32768)
    const __bf16* hb = ws + HB_OFF;
    const __bf16* pb = ws + PB_OFF;
    const __bf16* gb = ws + GB_OFF;
    const __bf16* wp = ws + WP_OFF;
    const __bf16* zp = ws + ZP_OFF;

    int bid = blockIdx.x;
    int swz = (bid & 7) * 392 + (bid >> 3);  // bijective, 3136 = 8*392
    int t     = swz >> 6;
    int rem   = swz & 63;
    int mtile = rem >> 3, ntile = rem & 7;

    int tid  = threadIdx.x;
    int wave = tid >> 6, lane = tid & 63;
    int lg = lane >> 4, l16 = lane & 15;

    // ---- staging maps: per it, chunk = it*256+tid covers 16B of a slot
    const __bf16* pA[2][6];
    const __bf16* pB[2];
    int dstA[2], dstB[2];
#pragma unroll
    for (int it = 0; it < 2; ++it) {
        int chunk = it * 256 + tid;          // [0,512)
        int row   = chunk >> 2;              // [0,128)
        int k16   = chunk & 3;
        int ke    = (k16 ^ ((row >> 1) & 3)) * 8;   // swizzled k elem offset
        int b_ = mtile * 2 + (row >> 6), n_ = row & 63, bt_ = b_ * TD + t;
        pA[it][0] = pb + ((bt_ * ND + n_) << 7) + ke;
        pA[it][1] = (t > 0)      ? hb + (((bt_ - 1) * ND + n_) << 7) + ke : zp + ke;
        pA[it][2] = hb + ((bt_ * ND + n_) << 7) + ke;
        pA[it][3] = (t < TD - 1) ? hb + (((bt_ + 1) * ND + n_) << 7) + ke : zp + ke;
        pA[it][4] = (n_ > 0)     ? hb + ((bt_ * ND + n_ - 1) << 7) + ke : zp + ke;
        pA[it][5] = gb + (bt_ << 7) + ke;
        int g_ = row >> 4, hc = row & 15;
        pB[it] = wp + (size_t)((t * 8 + g_) * 128 + ntile * 16 + hc) * 768 + ke;
        dstA[it] = chunk * 8;                // elems within A slot
        dstB[it] = 16384 + chunk * 8;        // B region base (elems) + chunk
    }

    // ---- fragment read byte-offsets (within a slot pair; B folded +32768)
    int rbA[2], rbB[8];
#pragma unroll
    for (int mi = 0; mi < 2; ++mi) {
        int row = wave * 32 + mi * 16 + l16;
        rbA[mi] = row * 64 + ((lg ^ ((row >> 1) & 3)) << 4);
    }
#pragma unroll
    for (int g = 0; g < 8; ++g) {
        int row = g * 16 + l16;
        rbB[g] = 32768 + row * 64 + ((lg ^ ((row >> 1) & 3)) << 4);
    }

    f32x4 acc[2][8];
    const f32x4 vzero = {0.f, 0.f, 0.f, 0.f};
#pragma unroll
    for (int mi = 0; mi < 2; ++mi)
#pragma unroll
        for (int g = 0; g < 8; ++g) acc[mi][g] = vzero;

#define STAGE(KS) do {                                                          \
        _Pragma("unroll")                                                       \
        for (int it = 0; it < 2; ++it) {                                        \
            gload16(pA[it][(KS) >> 2] + ((KS) & 3) * 32,                        \
                    smem + ((KS) & 3) * 4096 + dstA[it]);                       \
            gload16(pB[it] + (KS) * 32,                                         \
                    smem + ((KS) & 3) * 4096 + dstB[it]);                       \
        }                                                                       \
    } while (0)

    STAGE(0); STAGE(1); STAGE(2);
    asm volatile("s_waitcnt vmcnt(8)" ::: "memory");   // tile 0 landed (1,2 in flight)
    __builtin_amdgcn_s_barrier();

#pragma unroll
    for (int ks = 0; ks < 24; ++ks) {
        if (ks + 3 < 24) STAGE(ks + 3);
        const char* base = (const char*)smem + (ks & 3) * 8192;
        bf16x8 af[2], bfr[8];
        af[0] = *(const bf16x8*)(base + rbA[0]);
        af[1] = *(const bf16x8*)(base + rbA[1]);
#pragma unroll
        for (int g = 0; g < 8; ++g)
            bfr[g] = *(const bf16x8*)(base + rbB[g]);
#pragma unroll
        for (int g = 0; g < 8; ++g) {
            acc[0][g] = __builtin_amdgcn_mfma_f32_16x16x32_bf16(af[0], bfr[g], acc[0][g], 0, 0, 0);
            acc[1][g] = __builtin_amdgcn_mfma_f32_16x16x32_bf16(af[1], bfr[g], acc[1][g], 0, 0, 0);
        }
        if (ks < 23) {
            if (ks < 21)       asm volatile("s_waitcnt vmcnt(8)" ::: "memory");
            else if (ks == 21) asm volatile("s_waitcnt vmcnt(4)" ::: "memory");
            else               asm volatile("s_waitcnt vmcnt(0)" ::: "memory");
            __builtin_amdgcn_s_barrier();
        }
    }
#undef STAGE

    // ---- epilogue: gates + cell update, in-register (8 gates per lane) ----
    const int hcol = ntile * 16 + l16;
    float bv[8];
#pragma unroll
    for (int g = 0; g < 8; ++g) bv[g] = bias[(g * TD + t) * HD + hcol];

#pragma unroll
    for (int mi = 0; mi < 2; ++mi) {
#pragma unroll
        for (int r = 0; r < 4; ++r) {
            int RG = mtile * 128 + wave * 32 + mi * 16 + lg * 4 + r;
            int b  = RG >> 6, nn = RG & 63;
            int bt = b * TD + t;
            int base = ((bt * ND + nn) << 7) + hcol;
            float pre[8];
#pragma unroll
            for (int g = 0; g < 8; ++g) pre[g] = acc[mi][g][r] + bv[g];
            float i_  = sigf(pre[0]);
            float flt = sigf(pre[1]);
            float fft = sigf(pre[2]);
            float frt = sigf(pre[3]);
            float fs  = sigf(pre[4]);
            float gn  = sigf(pre[5]);
            float on  = sigf(pre[6]);
            float cn  = tanhf_fast(pre[7]);
            float ccur = c_h[base];
            float ctb  = (t > 0)      ? c_h[base - ND * HD] : 0.f;
            float cta  = (t < TD - 1) ? c_h[base + ND * HD] : 0.f;
            float csb  = (nn > 0)     ? c_h[base - HD]      : 0.f;
            float cg   = c_g_t[(bt << 7) + hcol];
            float cnew = i_ * cn + flt * ctb + fft * ccur + frt * cta + fs * csb + gn * cg;
            float hnew = on * tanhf_fast(cnew);
            out[OUT_H  + base] = hnew;
            out[OUT_CH + base] = cnew;
        }
    }
}

// ---------------------------------------------------------------------------
// Phase 2 (v2): grid 49 t x 4 bq; block = 4 b's (1 wave each). Stages the six
// 128x128 matrices ONCE per block (vs once per (b,t) before). hm from the
// staged h_new tile; dots in-block; f_gtf via MFMA; wave-local bone-mean.
// ---------------------------------------------------------------------------
__global__ __launch_bounds__(256, 1) void phase2_kernel(
    const float* __restrict__ g_t, const float* __restrict__ c_g_t,
    const float* __restrict__ Wg,  const float* __restrict__ Zg,
    const float* __restrict__ bg,  float* __restrict__ out)
{
    extern __shared__ char sm2[];
    __bf16* A2  = (__bf16*)sm2;                       // [256][136] h_new bf16
    __bf16* Wb  = (__bf16*)(sm2 + 69632);             // [128][136] staging
    float*  gts = (float*)(sm2 + 69632 + 34816);      // [4][128]
    float*  hm  = (float*)(sm2 + 69632 + 34816 + 2048);
    float*  dts = (float*)(sm2 + 69632 + 34816 + 4096); // [5][4][128]

    int bid = blockIdx.x;                 // 196
    int t = bid >> 2, bq = bid & 3;
    int tid = threadIdx.x;
    int wv = tid >> 6, lane = tid & 63, lg = lane >> 4, l16 = lane & 15;

    const float* hn  = out + OUT_H;
    const float* chn = out + OUT_CH;

    // ---- stage h_new (4 b x 64 n = 256 rows x 128) f32 -> bf16
#pragma unroll
    for (int j = 0; j < 32; ++j) {
        int fid = j * 256 + tid;              // [0,8192) f32x4 slots
        int r = fid >> 5, k = (fid & 31) << 2;
        int b = bq * 4 + (r >> 6), n = r & 63, bt = b * TD + t;
        f32x4 v = *(const f32x4*)(hn + ((bt * ND + n) << 7) + k);
        bf16x4 w;
        w[0] = (__bf16)v[0]; w[1] = (__bf16)v[1]; w[2] = (__bf16)v[2]; w[3] = (__bf16)v[3];
        *(bf16x4*)(A2 + r * KPAD + k) = w;
    }
#pragma unroll
    for (int j = 0; j < 2; ++j) {
        int idx = j * 256 + tid;              // [0,512)
        int b4 = idx >> 7, c = idx & 127;
        gts[idx] = g_t[(((bq * 4 + b4) * TD + t) << 7) + c];
    }
    __syncthreads();

    // ---- hm[b][c] = mean over 64 bones
#pragma unroll
    for (int j = 0; j < 2; ++j) {
        int idx = j * 256 + tid;
        int b4 = idx >> 7, c = idx & 127;
        float s = 0.f;
        for (int n = 0; n < 64; ++n) s += (float)A2[(b4 * 64 + n) * KPAD + c];
        hm[idx] = s * (1.f / 64.f);
    }
    __syncthreads();

    // ---- 5 dot products: m 0-2: g_t . Zg[m]; m 3,4: hm . Wg[m-2]
    for (int m = 0; m < 5; ++m) {
        const float* M = (m < 3) ? (Zg + ((size_t)(m * TD + t) << 14))
                                 : (Wg + ((size_t)((m - 2) * TD + t) << 14));
#pragma unroll
        for (int j = 0; j < 16; ++j) {
            int fid = j * 256 + tid;
            int k = fid >> 5, c4 = (fid & 31) << 2;
            f32x4 v = *(const f32x4*)(M + (k << 7) + c4);
            bf16x4 w;
            w[0] = (__bf16)v[0]; w[1] = (__bf16)v[1]; w[2] = (__bf16)v[2]; w[3] = (__bf16)v[3];
            *(bf16x4*)(Wb + k * KPAD + c4) = w;
        }
        __syncthreads();
        const float* vec = (m >= 3) ? hm : gts;
#pragma unroll
        for (int j = 0; j < 2; ++j) {
            int idx = j * 256 + tid;
            int b4 = idx >> 7, c = idx & 127;
            float s = 0.f;
            for (int k = 0; k < 128; ++k) s += vec[b4 * 128 + k] * (float)Wb[k * KPAD + c];
            dts[(m * 4 + b4) * 128 + c] = s;
        }
        __syncthreads();
    }

    // ---- stage Wg0 transposed: Wb[c][k]
    {
        const float* M = Wg + ((size_t)t << 14);
#pragma unroll
        for (int j = 0; j < 16; ++j) {
            int fid = j * 256 + tid;
            int k = fid >> 5, q = fid & 31;
            f32x4 v = *(const f32x4*)(M + (k << 7) + q * 4);
            int cb = q * 4;
            Wb[(cb + 0) * KPAD + k] = (__bf16)v[0];
            Wb[(cb + 1) * KPAD + k] = (__bf16)v[1];
            Wb[(cb + 2) * KPAD + k] = (__bf16)v[2];
            Wb[(cb + 3) * KPAD + k] = (__bf16)v[3];
        }
        __syncthreads();
    }

    // ---- MFMA: wave wv = b; rows 64 x cols 128, K=128
    f32x4 acc[4][8];
    const f32x4 vzero = {0.f, 0.f, 0.f, 0.f};
#pragma unroll
    for (int mi = 0; mi < 4; ++mi)
#pragma unroll
        for (int ni = 0; ni < 8; ++ni) acc[mi][ni] = vzero;
#pragma unroll
    for (int ks = 0; ks < 4; ++ks) {
        int kb = ks * 32 + lg * 8;
        bf16x8 a[4];
#pragma unroll
        for (int mi = 0; mi < 4; ++mi)
            a[mi] = *(const bf16x8*)(A2 + (wv * 64 + mi * 16 + l16) * KPAD + kb);
#pragma unroll
        for (int ni = 0; ni < 8; ++ni) {
            bf16x8 bfr = *(const bf16x8*)(Wb + (ni * 16 + l16) * KPAD + kb);
#pragma unroll
            for (int mi = 0; mi < 4; ++mi)
                acc[mi][ni] = __builtin_amdgcn_mfma_f32_16x16x32_bf16(a[mi], bfr, acc[mi][ni], 0, 0, 0);
        }
    }

    // ---- epilogue: f_gtf, bone-mean, g/o gates
    int b = bq * 4 + wv, bt = b * TD + t;
#pragma unroll
    for (int ni = 0; ni < 8; ++ni) {
        int col = ni * 16 + l16;
        float z = dts[(0 * 4 + wv) * 128 + col] + bg[t * HD + col];
        float macc = 0.f;
#pragma unroll
        for (int mi = 0; mi < 4; ++mi) {
#pragma unroll
            for (int r = 0; r < 4; ++r) {
                int row = mi * 16 + lg * 4 + r;
                float f  = sigf(acc[mi][ni][r] + z);
                float cv = chn[((bt * ND + row) << 7) + col];
                macc += f * cv;
            }
        }
        macc += __shfl_xor(macc, 16, 64);
        macc += __shfl_xor(macc, 32, 64);
        if (lg == 0) {
            float Mn  = macc * (1.f / 64.f);
            float g_g = sigf(dts[(3 * 4 + wv) * 128 + col] + dts[(1 * 4 + wv) * 128 + col]
                             + bg[(TD + t) * HD + col]);
            float o_g = sigf(dts[(4 * 4 + wv) * 128 + col] + dts[(2 * 4 + wv) * 128 + col]
                             + bg[(2 * TD + t) * HD + col]);
            float cgt = c_g_t[(bt << 7) + col];
            float cgn = Mn + g_g * cgt;
            out[OUT_G  + (bt << 7) + col] = tanhf_fast(cgn) * o_g;
            out[OUT_CG + (bt << 7) + col] = cgn;
        }
    }
}

extern "C" void kernel_launch(void* const* d_in, const int* in_sizes, int n_in,
                              void* d_out, int out_size, void* d_ws, size_t ws_size,
                              hipStream_t stream) {
    const float* h     = (const float*)d_in[0];
    const float* c_h   = (const float*)d_in[1];
    const float* p     = (const float*)d_in[2];
    const float* g_t   = (const float*)d_in[3];
    const float* c_g_t = (const float*)d_in[4];
    const float* U     = (const float*)d_in[5];
    const float* Wt    = (const float*)d_in[6];
    const float* Ws    = (const float*)d_in[7];
    const float* Zt    = (const float*)d_in[8];
    const float* b     = (const float*)d_in[9];
    const float* Wg    = (const float*)d_in[10];
    const float* Zg    = (const float*)d_in[11];
    const float* bg    = (const float*)d_in[12];
    float* out = (float*)d_out;
    __bf16* ws = (__bf16*)d_ws;

    prep_acts<<<12644, 256, 0, stream>>>(h, p, g_t, ws);
    prep_w<<<TD * 8 * 12, 256, 0, stream>>>(U, Wt, Ws, Zt, ws + WP_OFF);

    (void)hipFuncSetAttribute(reinterpret_cast<const void*>(phase1_kernel),
                              hipFuncAttributeMaxDynamicSharedMemorySize, LDS1_BYTES);
    (void)hipFuncSetAttribute(reinterpret_cast<const void*>(phase2_kernel),
                              hipFuncAttributeMaxDynamicSharedMemorySize, LDS2_BYTES);
    phase1_kernel<<<TD * 64, 256, LDS1_BYTES, stream>>>(ws, c_h, c_g_t, b, out);
    phase2_kernel<<<TD * 4, 256, LDS2_BYTES, stream>>>(g_t, c_g_t, Wg, Zg, bg, out);
}